// Round 1
// baseline (2069.883 us; speedup 1.0000x reference)
//
#include <hip/hip_runtime.h>
#include <math.h>

#define BB 64
#define KV 128
#define ME 256
#define NH 256
#define DC 684
#define DA 512
#define MC 256
#define HH_ 16
#define WW_ 48
#define HW_ 768

// workspace layout (floats)
#define WS_G   0                   // 512*9
#define WS_RB  (WS_G + 4608)       // rowbias 64*512
#define WS_EMB (WS_RB + 32768)     // 64*256
#define WS_SH  (WS_EMB + 16384)    // 64*256
#define WS_AL  (WS_SH + 16384)     // 64*768 alpha logits
#define WS_CT  (WS_AL + 49152)     // 64*684

// ---------------- K0: G[a][k] = sum_m Uf[a,m] * convQ[m,k] ----------------
__global__ __launch_bounds__(256) void k_G(const float* __restrict__ Uf,
                                           const float* __restrict__ convQ,
                                           float* __restrict__ G) {
    int idx = blockIdx.x * 256 + threadIdx.x;
    if (idx >= DA * 9) return;
    int a = idx / 9, k = idx % 9;
    float s = 0.f;
    for (int m = 0; m < MC; m++) s += Uf[a * MC + m] * convQ[m * 9 + k];
    G[idx] = s;
}

// ---------------- K1: embedding + GRU1 + rowbias (Wa_h1 + biases) ----------
__global__ __launch_bounds__(256) void k_pre(
    const int* __restrict__ y, const float* __restrict__ y_mask,
    const float* __restrict__ emb, const float* __restrict__ W_ih1,
    const float* __restrict__ W_hh1, const float* __restrict__ b_ih1,
    const float* __restrict__ b_hh1, const float* __restrict__ pre_hidden,
    const float* __restrict__ Wa, const float* __restrict__ conv_Ua_b,
    const float* __restrict__ Uf_b, float* __restrict__ embedded,
    float* __restrict__ s_hat, float* __restrict__ rowbias) {
    int b = blockIdx.x;
    int t = threadIdx.x;
    __shared__ float x[ME], h[NH], gi[3 * NH], gh[3 * NH], sh[NH];
    int yb = y[b];
    x[t] = emb[yb * ME + t];
    h[t] = pre_hidden[b * NH + t];
    embedded[b * ME + t] = x[t];
    __syncthreads();
    for (int r = t; r < 3 * NH; r += 256) {
        float sgi = b_ih1[r], sgh = b_hh1[r];
        const float* wi = &W_ih1[r * ME];
        const float* wh = &W_hh1[r * NH];
        for (int k = 0; k < ME; k++) sgi += wi[k] * x[k];
        for (int k = 0; k < NH; k++) sgh += wh[k] * h[k];
        gi[r] = sgi;
        gh[r] = sgh;
    }
    __syncthreads();
    {
        float r = 1.f / (1.f + expf(-(gi[t] + gh[t])));
        float z = 1.f / (1.f + expf(-(gi[NH + t] + gh[NH + t])));
        float n = tanhf(gi[2 * NH + t] + r * gh[2 * NH + t]);
        float sv = (1.f - z) * n + z * h[t];
        float m = y_mask[b];
        sv = m * sv + (1.f - m) * h[t];
        sh[t] = sv;
        s_hat[b * NH + t] = sv;
    }
    __syncthreads();
    for (int a = t; a < DA; a += 256) {
        float acc = conv_Ua_b[a] + Uf_b[a];
        const float* wa = &Wa[a * NH];
        for (int k = 0; k < NH; k++) acc += wa[k] * sh[k];
        rowbias[b * DA + a] = acc;
    }
}

// ---------------- K2: fused attention-energy GEMM + epilogue ---------------
// per block: b = blockIdx.y, 32 positions (p0..p0+31) x all 512 a's.
// acc[8][8] per thread: a = ty*8+i, p = p0+tx*8+j. K-loop over 684 d's.
#define KT 16
#define UAS 516  // padded LDS stride for ua tile
#define CXS 36   // padded LDS stride for ctx tile
__global__ __launch_bounds__(256) void k_att(
    const float* __restrict__ ctx, const float* __restrict__ Ua,
    const float* __restrict__ G, const float* __restrict__ rb,
    const float* __restrict__ va, const float* __restrict__ va_b,
    const float* __restrict__ apast, float* __restrict__ alogit) {
    __shared__ float ua_t[KT * UAS];
    __shared__ float cx_t[KT * CXS];
    __shared__ float ap_s[18 * 50];
    __shared__ float part_s[64 * 32];
    int b = blockIdx.y;
    int p0 = blockIdx.x * 32;
    int t = threadIdx.x;
    int tx = t & 3, ty = t >> 2;

    for (int idx = t; idx < 18 * 50; idx += 256) {
        int hh = idx / 50, ww = idx % 50;
        float v = 0.f;
        if (hh >= 1 && hh <= HH_ && ww >= 1 && ww <= WW_)
            v = apast[b * HW_ + (hh - 1) * WW_ + (ww - 1)];
        ap_s[idx] = v;
    }

    float acc[8][8];
#pragma unroll
    for (int i = 0; i < 8; i++)
#pragma unroll
        for (int j = 0; j < 8; j++) acc[i][j] = 0.f;

    for (int d0 = 0; d0 < DC; d0 += KT) {
        __syncthreads();
#pragma unroll
        for (int i = 0; i < 32; i++) {
            int idx = i * 256 + t;
            int aa = idx >> 4, kt = idx & 15;
            int d = d0 + kt;
            ua_t[kt * UAS + aa] = (d < DC) ? Ua[aa * DC + d] : 0.f;
        }
#pragma unroll
        for (int i = 0; i < 2; i++) {
            int idx = i * 256 + t;
            int kt = idx >> 5, pp = idx & 31;
            int d = d0 + kt;
            cx_t[kt * CXS + pp] = (d < DC) ? ctx[(b * DC + d) * HW_ + p0 + pp] : 0.f;
        }
        __syncthreads();
#pragma unroll
        for (int kt = 0; kt < KT; kt++) {
            float av[8], pv[8];
#pragma unroll
            for (int i = 0; i < 8; i++) av[i] = ua_t[kt * UAS + ty * 8 + i];
#pragma unroll
            for (int j = 0; j < 8; j++) pv[j] = cx_t[kt * CXS + tx * 8 + j];
#pragma unroll
            for (int i = 0; i < 8; i++)
#pragma unroll
                for (int j = 0; j < 8; j++) acc[i][j] += av[i] * pv[j];
        }
    }

    // epilogue: + rowbias + 9-tap coverage, tanh, dot with va
    float partial[8];
#pragma unroll
    for (int j = 0; j < 8; j++) partial[j] = 0.f;
#pragma unroll
    for (int i = 0; i < 8; i++) {
        int a = ty * 8 + i;
        float rbv = rb[b * DA + a];
        float vav = va[a];
        float g0 = G[a * 9 + 0], g1 = G[a * 9 + 1], g2 = G[a * 9 + 2];
        float g3 = G[a * 9 + 3], g4 = G[a * 9 + 4], g5 = G[a * 9 + 5];
        float g6 = G[a * 9 + 6], g7 = G[a * 9 + 7], g8 = G[a * 9 + 8];
#pragma unroll
        for (int j = 0; j < 8; j++) {
            int p = p0 + tx * 8 + j;
            int hh = p / WW_, ww = p % WW_;
            const float* ap = &ap_s[hh * 50 + ww];
            float cov = g0 * ap[0] + g1 * ap[1] + g2 * ap[2] + g3 * ap[50] +
                        g4 * ap[51] + g5 * ap[52] + g6 * ap[100] +
                        g7 * ap[101] + g8 * ap[102];
            float e = tanhf(acc[i][j] + rbv + cov);
            partial[j] += vav * e;
        }
    }
#pragma unroll
    for (int j = 0; j < 8; j++) part_s[ty * 32 + tx * 8 + j] = partial[j];
    __syncthreads();
    if (t < 32) {
        float s = va_b[0];
        for (int q = 0; q < 64; q++) s += part_s[q * 32 + t];
        alogit[b * HW_ + p0 + t] = s;
    }
}

// ---------------- K3: softmax over 768 positions per b ---------------------
__global__ __launch_bounds__(256) void k_softmax(const float* __restrict__ alogit,
                                                 float* __restrict__ alpha) {
    __shared__ float red[16];
    int b = blockIdx.x, t = threadIdx.x;
    float v[3];
    float mx = -1e30f;
    for (int i = 0; i < 3; i++) {
        v[i] = alogit[b * HW_ + i * 256 + t];
        mx = fmaxf(mx, v[i]);
    }
    for (int off = 32; off > 0; off >>= 1) mx = fmaxf(mx, __shfl_down(mx, off));
    if ((t & 63) == 0) red[t >> 6] = mx;
    __syncthreads();
    if (t == 0) red[0] = fmaxf(fmaxf(red[0], red[1]), fmaxf(red[2], red[3]));
    __syncthreads();
    mx = red[0];
    float sum = 0.f;
    for (int i = 0; i < 3; i++) {
        v[i] = expf(v[i] - mx);
        sum += v[i];
    }
    for (int off = 32; off > 0; off >>= 1) sum += __shfl_down(sum, off);
    if ((t & 63) == 0) red[8 + (t >> 6)] = sum;
    __syncthreads();
    if (t == 0) red[8] = red[8] + red[9] + red[10] + red[11];
    __syncthreads();
    float inv = 1.f / red[8];
    for (int i = 0; i < 3; i++) alpha[b * HW_ + i * 256 + t] = v[i] * inv;
}

// ---------------- K4: ct[b,d] = sum_p ctx[b,d,p] * alpha[b,p] --------------
__global__ __launch_bounds__(256) void k_ct(const float* __restrict__ ctx,
                                            const float* __restrict__ alpha,
                                            float* __restrict__ ct) {
    __shared__ float al_s[HW_];
    int b = blockIdx.y;
    int dc0 = blockIdx.x * 114;
    int t = threadIdx.x;
    for (int i = t; i < HW_; i += 256) al_s[i] = alpha[b * HW_ + i];
    __syncthreads();
    int wave = t >> 6, lane = t & 63;
    for (int d = dc0 + wave; d < dc0 + 114; d += 4) {
        const float* row = &ctx[(b * DC + d) * HW_];
        float s = 0.f;
#pragma unroll
        for (int q = 0; q < 12; q++) s += row[lane + q * 64] * al_s[lane + q * 64];
        for (int off = 32; off > 0; off >>= 1) s += __shfl_down(s, off);
        if (lane == 0) ct[b * DC + d] = s;
    }
}

// ---------------- K5: GRU2 + logits + maxout + output head -----------------
__global__ __launch_bounds__(256) void k_final(
    const float* __restrict__ ctw, const float* __restrict__ s_hat,
    const float* __restrict__ emb_w, const float* __restrict__ y_mask,
    const float* __restrict__ W_ih2, const float* __restrict__ W_hh2,
    const float* __restrict__ b_ih2, const float* __restrict__ b_hh2,
    const float* __restrict__ Wct, const float* __restrict__ Wct_b,
    const float* __restrict__ Wht, const float* __restrict__ Wht_b,
    const float* __restrict__ W0, const float* __restrict__ W0_b,
    float* __restrict__ out) {
    __shared__ float ct_s[DC], sh_s[NH], gi2[3 * NH], gh2[3 * NH], s_s[NH],
        lg[ME], mo[ME / 2];
    int b = blockIdx.x, t = threadIdx.x;
    for (int i = t; i < DC; i += 256) ct_s[i] = ctw[b * DC + i];
    sh_s[t] = s_hat[b * NH + t];
    __syncthreads();
    for (int r = t; r < 3 * NH; r += 256) {
        float si = b_ih2[r];
        const float* wi = &W_ih2[r * DC];
        for (int k = 0; k < DC; k++) si += wi[k] * ct_s[k];
        gi2[r] = si;
        float sh2 = b_hh2[r];
        const float* wh = &W_hh2[r * NH];
        for (int k = 0; k < NH; k++) sh2 += wh[k] * sh_s[k];
        gh2[r] = sh2;
    }
    __syncthreads();
    {
        float r = 1.f / (1.f + expf(-(gi2[t] + gh2[t])));
        float z = 1.f / (1.f + expf(-(gi2[NH + t] + gh2[NH + t])));
        float n = tanhf(gi2[2 * NH + t] + r * gh2[2 * NH + t]);
        float sv = (1.f - z) * n + z * sh_s[t];
        float m = y_mask[b];
        sv = m * sv + (1.f - m) * sh_s[t];
        s_s[t] = sv;
        out[8192 + b * NH + t] = sv;  // output 1: s
    }
    __syncthreads();
    {
        float acc = Wct_b[t] + Wht_b[t] + emb_w[b * ME + t];
        const float* wr = &Wct[t * DC];
        for (int k = 0; k < DC; k++) acc += wr[k] * ct_s[k];
        const float* wh = &Wht[t * NH];
        for (int k = 0; k < NH; k++) acc += wh[k] * s_s[k];
        lg[t] = acc;
    }
    __syncthreads();
    if (t < 128) mo[t] = fmaxf(lg[2 * t], lg[2 * t + 1]);
    __syncthreads();
    if (t < 128) {
        float acc = W0_b[t];
        const float* w0 = &W0[t * 128];
        for (int k = 0; k < 128; k++) acc += w0[k] * mo[k];
        out[b * KV + t] = acc;  // output 0: out
    }
}

extern "C" void kernel_launch(void* const* d_in, const int* in_sizes, int n_in,
                              void* d_out, int out_size, void* d_ws,
                              size_t ws_size, hipStream_t stream) {
    const int* y = (const int*)d_in[0];
    const float* y_mask = (const float*)d_in[1];
    const float* context = (const float*)d_in[2];
    const float* pre_hidden = (const float*)d_in[3];
    const float* alpha_past = (const float*)d_in[4];
    const float* emb = (const float*)d_in[5];
    const float* W_ih1 = (const float*)d_in[6];
    const float* W_hh1 = (const float*)d_in[7];
    const float* b_ih1 = (const float*)d_in[8];
    const float* b_hh1 = (const float*)d_in[9];
    const float* conv_Ua_w = (const float*)d_in[10];
    const float* conv_Ua_b = (const float*)d_in[11];
    const float* Wa = (const float*)d_in[12];
    const float* conv_Q_w = (const float*)d_in[13];
    const float* Uf = (const float*)d_in[14];
    const float* Uf_b = (const float*)d_in[15];
    const float* va = (const float*)d_in[16];
    const float* va_b = (const float*)d_in[17];
    const float* W_ih2 = (const float*)d_in[18];
    const float* W_hh2 = (const float*)d_in[19];
    const float* b_ih2 = (const float*)d_in[20];
    const float* b_hh2 = (const float*)d_in[21];
    const float* Wct = (const float*)d_in[22];
    const float* Wct_b = (const float*)d_in[23];
    const float* Wht = (const float*)d_in[24];
    const float* Wht_b = (const float*)d_in[25];
    const float* W0 = (const float*)d_in[26];
    const float* W0_b = (const float*)d_in[27];

    float* ws = (float*)d_ws;
    float* out = (float*)d_out;
    float* G = ws + WS_G;
    float* rb = ws + WS_RB;
    float* embedded = ws + WS_EMB;
    float* s_hat = ws + WS_SH;
    float* alogit = ws + WS_AL;
    float* ctv = ws + WS_CT;
    float* alpha_out = out + 24576;  // output 2 region, also consumed by k_ct

    k_G<<<dim3(18), dim3(256), 0, stream>>>(Uf, conv_Q_w, G);
    k_pre<<<dim3(64), dim3(256), 0, stream>>>(y, y_mask, emb, W_ih1, W_hh1,
                                              b_ih1, b_hh1, pre_hidden, Wa,
                                              conv_Ua_b, Uf_b, embedded, s_hat,
                                              rb);
    k_att<<<dim3(24, 64), dim3(256), 0, stream>>>(context, conv_Ua_w, G, rb, va,
                                                  va_b, alpha_past, alogit);
    k_softmax<<<dim3(64), dim3(256), 0, stream>>>(alogit, alpha_out);
    k_ct<<<dim3(6, 64), dim3(256), 0, stream>>>(context, alpha_out, ctv);
    k_final<<<dim3(64), dim3(256), 0, stream>>>(
        ctv, s_hat, embedded, y_mask, W_ih2, W_hh2, b_ih2, b_hh2, Wct, Wct_b,
        Wht, Wht_b, W0, W0_b, out);
}

// Round 2
// 372.417 us; speedup vs baseline: 5.5580x; 5.5580x over previous
//
#include <hip/hip_runtime.h>
#include <hip/hip_bf16.h>
#include <math.h>

#define BB 64
#define KV 128
#define ME 256
#define NH 256
#define DC 684
#define DA 512
#define MC 256
#define HH_ 16
#define WW_ 48
#define HW_ 768

typedef __attribute__((ext_vector_type(8))) short bf16x8;
typedef __attribute__((ext_vector_type(4))) float f32x4;

// workspace layout (floats)
#define WS_G    0                    // 512*9
#define WS_RB   (WS_G + 4608)        // rowbias 64*512
#define WS_EMB  (WS_RB + 32768)      // 64*256
#define WS_SH   (WS_EMB + 16384)     // 64*256
#define WS_AL   (WS_SH + 16384)      // 64*768 alpha logits
#define WS_CT   (WS_AL + 49152)      // 64*684
#define WS_UA16 (WS_CT + 43776)      // 512*704 bf16 = 180224 floats

// ---------------- K0: G[a][k] = sum_m Uf[a,m] * convQ[m,k] ----------------
__global__ __launch_bounds__(256) void k_G(const float* __restrict__ Uf,
                                           const float* __restrict__ convQ,
                                           float* __restrict__ G) {
    int idx = blockIdx.x * 256 + threadIdx.x;
    if (idx >= DA * 9) return;
    int a = idx / 9, k = idx % 9;
    float s = 0.f;
    for (int m = 0; m < MC; m++) s += Uf[a * MC + m] * convQ[m * 9 + k];
    G[idx] = s;
}

// ---------------- K0b: Ua fp32 [512][684] -> bf16 [512][704] zero-padded ---
__global__ __launch_bounds__(256) void k_prepUa(const float* __restrict__ Ua,
                                                unsigned short* __restrict__ Ua16) {
    int idx = blockIdx.x * 256 + threadIdx.x;
    if (idx >= DA * 704) return;
    int a = idx / 704, d = idx % 704;
    float v = (d < DC) ? Ua[a * DC + d] : 0.f;
    __hip_bfloat16 h = __float2bfloat16(v);
    Ua16[idx] = *reinterpret_cast<unsigned short*>(&h);
}

// ---------------- K1: embedding + GRU1 + rowbias (Wa_h1 + biases) ----------
__global__ __launch_bounds__(256) void k_pre(
    const int* __restrict__ y, const float* __restrict__ y_mask,
    const float* __restrict__ emb, const float* __restrict__ W_ih1,
    const float* __restrict__ W_hh1, const float* __restrict__ b_ih1,
    const float* __restrict__ b_hh1, const float* __restrict__ pre_hidden,
    const float* __restrict__ Wa, const float* __restrict__ conv_Ua_b,
    const float* __restrict__ Uf_b, float* __restrict__ embedded,
    float* __restrict__ s_hat, float* __restrict__ rowbias) {
    int b = blockIdx.x;
    int t = threadIdx.x;
    __shared__ float x[ME], h[NH], gi[3 * NH], gh[3 * NH], sh[NH];
    int yb = y[b];
    x[t] = emb[yb * ME + t];
    h[t] = pre_hidden[b * NH + t];
    embedded[b * ME + t] = x[t];
    __syncthreads();
    for (int r = t; r < 3 * NH; r += 256) {
        float sgi = b_ih1[r], sgh = b_hh1[r];
        const float* wi = &W_ih1[r * ME];
        const float* wh = &W_hh1[r * NH];
        for (int k = 0; k < ME; k++) sgi += wi[k] * x[k];
        for (int k = 0; k < NH; k++) sgh += wh[k] * h[k];
        gi[r] = sgi;
        gh[r] = sgh;
    }
    __syncthreads();
    {
        float r = 1.f / (1.f + expf(-(gi[t] + gh[t])));
        float z = 1.f / (1.f + expf(-(gi[NH + t] + gh[NH + t])));
        float n = tanhf(gi[2 * NH + t] + r * gh[2 * NH + t]);
        float sv = (1.f - z) * n + z * h[t];
        float m = y_mask[b];
        sv = m * sv + (1.f - m) * h[t];
        sh[t] = sv;
        s_hat[b * NH + t] = sv;
    }
    __syncthreads();
    for (int a = t; a < DA; a += 256) {
        float acc = conv_Ua_b[a] + Uf_b[a];
        const float* wa = &Wa[a * NH];
        for (int k = 0; k < NH; k++) acc += wa[k] * sh[k];
        rowbias[b * DA + a] = acc;
    }
}

// ---------------- K2: fused attention-energy GEMM (bf16 MFMA) --------------
// block: b = blockIdx.y, p-tile of 64 (blockIdx.x), all 512 a's. K over 684 d.
// wave w owns a in [w*128, w*128+128), all 64 p: 8 m-frags x 4 n-frags,
// acc[8][4] f32x4. LDS rows padded to 40 bf16 (80B): 16B-aligned b128 reads,
// bank-uniform (8 req/bank = minimum).
#define LDW 40
__global__ __launch_bounds__(256) void k_att(
    const unsigned short* __restrict__ Ua16, const float* __restrict__ ctx,
    const float* __restrict__ G, const float* __restrict__ rb,
    const float* __restrict__ va, const float* __restrict__ va_b,
    const float* __restrict__ apast, float* __restrict__ alogit) {
    __shared__ __attribute__((aligned(16))) short lsA[DA * LDW];
    __shared__ __attribute__((aligned(16))) short lsB[64 * LDW];
    __shared__ float ap_s[18 * 50];
    __shared__ float part_s[4 * 64];
    int b = blockIdx.y;
    int p0 = blockIdx.x * 64;
    int t = threadIdx.x;
    int w = t >> 6, lane = t & 63;
    int l15 = lane & 15, lg = lane >> 4;

    // alpha_past halo (18 x 50 with zero border)
    for (int idx = t; idx < 900; idx += 256) {
        int hh = idx / 50, ww = idx % 50;
        float v = 0.f;
        if (hh >= 1 && hh <= HH_ && ww >= 1 && ww <= WW_)
            v = apast[b * HW_ + (hh - 1) * WW_ + (ww - 1)];
        ap_s[idx] = v;
    }

    f32x4 acc[8][4];
#pragma unroll
    for (int i = 0; i < 8; i++)
#pragma unroll
        for (int j = 0; j < 4; j++) acc[i][j] = {0.f, 0.f, 0.f, 0.f};

    int b_kp = t >> 4;   // k-pair 0..15
    int b_pq = t & 15;   // p-quad 0..15

    for (int d0 = 0; d0 < DC; d0 += 32) {
        __syncthreads();
        // stage A: Ua16[512][704] -> lsA[512][LDW], 8 b128 copies/thread
#pragma unroll
        for (int i = 0; i < 8; i++) {
            int idx = i * 256 + t;
            int row = idx >> 2, q = idx & 3;
            bf16x8 v = *(const bf16x8*)(Ua16 + row * 704 + d0 + q * 8);
            *(bf16x8*)(lsA + row * LDW + q * 8) = v;
        }
        // stage B: ctx[b][d][p] -> lsB[p][k] (transpose + fp32->bf16 pack)
        {
            int d = d0 + 2 * b_kp;
            f32x4 fa = {0.f, 0.f, 0.f, 0.f}, fb = {0.f, 0.f, 0.f, 0.f};
            const float* src = ctx + ((long)b * DC + d) * HW_ + p0 + b_pq * 4;
            if (d < DC) fa = *(const f32x4*)(src);
            if (d + 1 < DC) fb = *(const f32x4*)(src + HW_);
#pragma unroll
            for (int j = 0; j < 4; j++) {
                __hip_bfloat16 lo = __float2bfloat16(fa[j]);
                __hip_bfloat16 hi = __float2bfloat16(fb[j]);
                unsigned lob = *reinterpret_cast<unsigned short*>(&lo);
                unsigned hib = *reinterpret_cast<unsigned short*>(&hi);
                ((unsigned*)lsB)[(b_pq * 4 + j) * (LDW / 2) + b_kp] =
                    lob | (hib << 16);
            }
        }
        __syncthreads();
        bf16x8 bfr[4];
#pragma unroll
        for (int j = 0; j < 4; j++)
            bfr[j] = *(const bf16x8*)(lsB + (j * 16 + l15) * LDW + lg * 8);
#pragma unroll
        for (int i = 0; i < 8; i++) {
            bf16x8 afr =
                *(const bf16x8*)(lsA + (w * 128 + i * 16 + l15) * LDW + lg * 8);
#pragma unroll
            for (int j = 0; j < 4; j++)
                acc[i][j] = __builtin_amdgcn_mfma_f32_16x16x32_bf16(
                    afr, bfr[j], acc[i][j], 0, 0, 0);
        }
    }

    // epilogue: + rowbias + 9-tap coverage, tanh, dot with va, reduce over a
    float partial[4] = {0.f, 0.f, 0.f, 0.f};
#pragma unroll
    for (int i = 0; i < 8; i++) {
#pragma unroll
        for (int r = 0; r < 4; r++) {
            int a = w * 128 + i * 16 + lg * 4 + r;
            float rbv = rb[b * DA + a];
            float vav = va[a];
            const float* Ga = G + a * 9;
            float g0 = Ga[0], g1 = Ga[1], g2 = Ga[2], g3 = Ga[3], g4 = Ga[4];
            float g5 = Ga[5], g6 = Ga[6], g7 = Ga[7], g8 = Ga[8];
#pragma unroll
            for (int j = 0; j < 4; j++) {
                int p = p0 + j * 16 + l15;
                int hh = p / WW_, ww = p % WW_;
                const float* ap = ap_s + hh * 50 + ww;
                float cov = g0 * ap[0] + g1 * ap[1] + g2 * ap[2] +
                            g3 * ap[50] + g4 * ap[51] + g5 * ap[52] +
                            g6 * ap[100] + g7 * ap[101] + g8 * ap[102];
                float e = tanhf(acc[i][j][r] + rbv + cov);
                partial[j] += vav * e;
            }
        }
    }
#pragma unroll
    for (int j = 0; j < 4; j++) {
        partial[j] += __shfl_xor(partial[j], 16);
        partial[j] += __shfl_xor(partial[j], 32);
    }
    if (lane < 16) {
#pragma unroll
        for (int j = 0; j < 4; j++) part_s[w * 64 + j * 16 + lane] = partial[j];
    }
    __syncthreads();
    if (t < 64) {
        float s = va_b[0] + part_s[t] + part_s[64 + t] + part_s[128 + t] +
                  part_s[192 + t];
        alogit[b * HW_ + p0 + t] = s;
    }
}

// ---------------- K3: softmax over 768 positions per b ---------------------
__global__ __launch_bounds__(256) void k_softmax(const float* __restrict__ alogit,
                                                 float* __restrict__ alpha) {
    __shared__ float red[16];
    int b = blockIdx.x, t = threadIdx.x;
    float v[3];
    float mx = -1e30f;
    for (int i = 0; i < 3; i++) {
        v[i] = alogit[b * HW_ + i * 256 + t];
        mx = fmaxf(mx, v[i]);
    }
    for (int off = 32; off > 0; off >>= 1) mx = fmaxf(mx, __shfl_down(mx, off));
    if ((t & 63) == 0) red[t >> 6] = mx;
    __syncthreads();
    if (t == 0) red[0] = fmaxf(fmaxf(red[0], red[1]), fmaxf(red[2], red[3]));
    __syncthreads();
    mx = red[0];
    float sum = 0.f;
    for (int i = 0; i < 3; i++) {
        v[i] = expf(v[i] - mx);
        sum += v[i];
    }
    for (int off = 32; off > 0; off >>= 1) sum += __shfl_down(sum, off);
    if ((t & 63) == 0) red[8 + (t >> 6)] = sum;
    __syncthreads();
    if (t == 0) red[8] = red[8] + red[9] + red[10] + red[11];
    __syncthreads();
    float inv = 1.f / red[8];
    for (int i = 0; i < 3; i++) alpha[b * HW_ + i * 256 + t] = v[i] * inv;
}

// ---------------- K4: ct[b,d] = sum_p ctx[b,d,p] * alpha[b,p] --------------
__global__ __launch_bounds__(256) void k_ct(const float* __restrict__ ctx,
                                            const float* __restrict__ alpha,
                                            float* __restrict__ ct) {
    __shared__ float al_s[HW_];
    int b = blockIdx.y;
    int dc0 = blockIdx.x * 114;
    int t = threadIdx.x;
    for (int i = t; i < HW_; i += 256) al_s[i] = alpha[b * HW_ + i];
    __syncthreads();
    int wave = t >> 6, lane = t & 63;
    for (int d = dc0 + wave; d < dc0 + 114; d += 4) {
        const float* row = &ctx[(b * DC + d) * HW_];
        float s = 0.f;
#pragma unroll
        for (int q = 0; q < 12; q++) s += row[lane + q * 64] * al_s[lane + q * 64];
        for (int off = 32; off > 0; off >>= 1) s += __shfl_down(s, off);
        if (lane == 0) ct[b * DC + d] = s;
    }
}

// ---------------- K5: GRU2 + logits + maxout + output head -----------------
__global__ __launch_bounds__(256) void k_final(
    const float* __restrict__ ctw, const float* __restrict__ s_hat,
    const float* __restrict__ emb_w, const float* __restrict__ y_mask,
    const float* __restrict__ W_ih2, const float* __restrict__ W_hh2,
    const float* __restrict__ b_ih2, const float* __restrict__ b_hh2,
    const float* __restrict__ Wct, const float* __restrict__ Wct_b,
    const float* __restrict__ Wht, const float* __restrict__ Wht_b,
    const float* __restrict__ W0, const float* __restrict__ W0_b,
    float* __restrict__ out) {
    __shared__ float ct_s[DC], sh_s[NH], gi2[3 * NH], gh2[3 * NH], s_s[NH],
        lg[ME], mo[ME / 2];
    int b = blockIdx.x, t = threadIdx.x;
    for (int i = t; i < DC; i += 256) ct_s[i] = ctw[b * DC + i];
    sh_s[t] = s_hat[b * NH + t];
    __syncthreads();
    for (int r = t; r < 3 * NH; r += 256) {
        float si = b_ih2[r];
        const float* wi = &W_ih2[r * DC];
        for (int k = 0; k < DC; k++) si += wi[k] * ct_s[k];
        gi2[r] = si;
        float sh2 = b_hh2[r];
        const float* wh = &W_hh2[r * NH];
        for (int k = 0; k < NH; k++) sh2 += wh[k] * sh_s[k];
        gh2[r] = sh2;
    }
    __syncthreads();
    {
        float r = 1.f / (1.f + expf(-(gi2[t] + gh2[t])));
        float z = 1.f / (1.f + expf(-(gi2[NH + t] + gh2[NH + t])));
        float n = tanhf(gi2[2 * NH + t] + r * gh2[2 * NH + t]);
        float sv = (1.f - z) * n + z * sh_s[t];
        float m = y_mask[b];
        sv = m * sv + (1.f - m) * sh_s[t];
        s_s[t] = sv;
        out[8192 + b * NH + t] = sv;  // output 1: s
    }
    __syncthreads();
    {
        float acc = Wct_b[t] + Wht_b[t] + emb_w[b * ME + t];
        const float* wr = &Wct[t * DC];
        for (int k = 0; k < DC; k++) acc += wr[k] * ct_s[k];
        const float* wh = &Wht[t * NH];
        for (int k = 0; k < NH; k++) acc += wh[k] * s_s[k];
        lg[t] = acc;
    }
    __syncthreads();
    if (t < 128) mo[t] = fmaxf(lg[2 * t], lg[2 * t + 1]);
    __syncthreads();
    if (t < 128) {
        float acc = W0_b[t];
        const float* w0 = &W0[t * 128];
        for (int k = 0; k < 128; k++) acc += w0[k] * mo[k];
        out[b * KV + t] = acc;  // output 0: out
    }
}

extern "C" void kernel_launch(void* const* d_in, const int* in_sizes, int n_in,
                              void* d_out, int out_size, void* d_ws,
                              size_t ws_size, hipStream_t stream) {
    const int* y = (const int*)d_in[0];
    const float* y_mask = (const float*)d_in[1];
    const float* context = (const float*)d_in[2];
    const float* pre_hidden = (const float*)d_in[3];
    const float* alpha_past = (const float*)d_in[4];
    const float* emb = (const float*)d_in[5];
    const float* W_ih1 = (const float*)d_in[6];
    const float* W_hh1 = (const float*)d_in[7];
    const float* b_ih1 = (const float*)d_in[8];
    const float* b_hh1 = (const float*)d_in[9];
    const float* conv_Ua_w = (const float*)d_in[10];
    const float* conv_Ua_b = (const float*)d_in[11];
    const float* Wa = (const float*)d_in[12];
    const float* conv_Q_w = (const float*)d_in[13];
    const float* Uf = (const float*)d_in[14];
    const float* Uf_b = (const float*)d_in[15];
    const float* va = (const float*)d_in[16];
    const float* va_b = (const float*)d_in[17];
    const float* W_ih2 = (const float*)d_in[18];
    const float* W_hh2 = (const float*)d_in[19];
    const float* b_ih2 = (const float*)d_in[20];
    const float* b_hh2 = (const float*)d_in[21];
    const float* Wct = (const float*)d_in[22];
    const float* Wct_b = (const float*)d_in[23];
    const float* Wht = (const float*)d_in[24];
    const float* Wht_b = (const float*)d_in[25];
    const float* W0 = (const float*)d_in[26];
    const float* W0_b = (const float*)d_in[27];

    float* ws = (float*)d_ws;
    float* out = (float*)d_out;
    float* G = ws + WS_G;
    float* rbias = ws + WS_RB;
    float* embedded = ws + WS_EMB;
    float* s_hat = ws + WS_SH;
    float* alogit = ws + WS_AL;
    float* ctv = ws + WS_CT;
    unsigned short* Ua16 = (unsigned short*)(ws + WS_UA16);
    float* alpha_out = out + 24576;  // output 2 region, also consumed by k_ct

    k_G<<<dim3(18), dim3(256), 0, stream>>>(Uf, conv_Q_w, G);
    k_prepUa<<<dim3((DA * 704 + 255) / 256), dim3(256), 0, stream>>>(conv_Ua_w,
                                                                     Ua16);
    k_pre<<<dim3(64), dim3(256), 0, stream>>>(y, y_mask, emb, W_ih1, W_hh1,
                                              b_ih1, b_hh1, pre_hidden, Wa,
                                              conv_Ua_b, Uf_b, embedded, s_hat,
                                              rbias);
    k_att<<<dim3(12, 64), dim3(256), 0, stream>>>(Ua16, context, G, rbias, va,
                                                  va_b, alpha_past, alogit);
    k_softmax<<<dim3(64), dim3(256), 0, stream>>>(alogit, alpha_out);
    k_ct<<<dim3(6, 64), dim3(256), 0, stream>>>(context, alpha_out, ctv);
    k_final<<<dim3(64), dim3(256), 0, stream>>>(
        ctv, s_hat, embedded, y_mask, W_ih2, W_hh2, b_ih2, b_hh2, Wct, Wct_b,
        Wht, Wht_b, W0, W0_b, out);
}

// Round 3
// 287.893 us; speedup vs baseline: 7.1898x; 1.2936x over previous
//
#include <hip/hip_runtime.h>
#include <hip/hip_bf16.h>
#include <math.h>

#define BB 64
#define KV 128
#define ME 256
#define NH 256
#define DC 684
#define DA 512
#define MC 256
#define HH_ 16
#define WW_ 48
#define HW_ 768
#define NS 22   // K-steps of 32 (684 -> 704 padded)

typedef __attribute__((ext_vector_type(8))) short bf16x8;
typedef __attribute__((ext_vector_type(4))) float f32x4;

// workspace layout (floats)
#define WS_G     0                    // 512*9
#define WS_RB    (WS_G + 4608)        // rowbias 64*512
#define WS_EMB   (WS_RB + 32768)      // 64*256
#define WS_SH    (WS_EMB + 16384)     // 64*256 s_hat
#define WS_AL    (WS_SH + 16384)      // 64*768 alpha logits
#define WS_CT    (WS_AL + 49152)      // 64*684 ct
#define WS_APACK (WS_CT + 43776)      // 22*512*32 bf16 = 180224 floats
#define WS_GI    (WS_APACK + 180224)  // 64*768
#define WS_GH    (WS_GI + 49152)      // 64*768
#define WS_LG    WS_GI                // logit 64*256 reuses GI after gru2

// ---------------- K0: G[a][k] = sum_m Uf[a,m] * convQ[m,k] ----------------
__global__ __launch_bounds__(256) void k_G(const float* __restrict__ Uf,
                                           const float* __restrict__ convQ,
                                           float* __restrict__ G) {
    int idx = blockIdx.x * 256 + threadIdx.x;
    if (idx >= DA * 9) return;
    int a = idx / 9, k = idx % 9;
    float s = 0.f;
    for (int m = 0; m < MC; m++) s += Uf[a * MC + m] * convQ[m * 9 + k];
    G[idx] = s;
}

// ------- K0b: Ua [512][684] fp32 -> A_pack[s][a][32k] bf16 (frag-major) ----
__global__ __launch_bounds__(256) void k_prepA(const float* __restrict__ Ua,
                                               unsigned short* __restrict__ Apack) {
    int idx = blockIdx.x * 256 + threadIdx.x;
    if (idx >= NS * DA * 32) return;
    int s = idx >> 14;           // /(512*32)
    int rem = idx & 16383;
    int a = rem >> 5, k = rem & 31;
    int d = s * 32 + k;
    float v = (d < DC) ? Ua[a * DC + d] : 0.f;
    __hip_bfloat16 h = __float2bfloat16(v);
    Apack[idx] = *reinterpret_cast<unsigned short*>(&h);
}

// ---------------- K0c: embedded[b][k] = emb[y[b]][k] -----------------------
__global__ __launch_bounds__(256) void k_emb(const int* __restrict__ y,
                                             const float* __restrict__ emb,
                                             float* __restrict__ embedded) {
    int b = blockIdx.x, t = threadIdx.x;
    embedded[b * ME + t] = emb[y[b] * ME + t];
}

// ------- rows-of-W kernel, K=256: out[b][r] = W[r]·X[b] + bias(+bias2) -----
// grid = nrows/4 blocks; 4 waves; wave = one row; lanes = b.
__global__ __launch_bounds__(256) void k_rows256(
    const float* __restrict__ X, const float* __restrict__ W,
    const float* __restrict__ bias, const float* __restrict__ bias2,
    float* __restrict__ out, int outStride) {
    __shared__ float Xs[64 * 257];
    __shared__ float ws_w[4 * 260];
    int t = threadIdx.x, w = t >> 6, lane = t & 63;
    for (int i = t; i < 64 * 256; i += 256) {
        int bb = i >> 8, k = i & 255;
        Xs[bb * 257 + k] = X[bb * 256 + k];
    }
    int r = blockIdx.x * 4 + w;
    *(f32x4*)(ws_w + w * 260 + lane * 4) = *(const f32x4*)(W + r * 256 + lane * 4);
    __syncthreads();
    const float* xrow = Xs + lane * 257;
    const float* wrow = ws_w + w * 260;
    float acc = 0.f;
#pragma unroll 8
    for (int k = 0; k < 256; k++) acc += wrow[k] * xrow[k];
    acc += bias[r];
    if (bias2) acc += bias2[r];
    out[lane * outStride + r] = acc;
}

// ------- rows-of-W kernel, K=684 (X = ct[64][684]), chunks of 228 ----------
__global__ __launch_bounds__(256) void k_rows684(
    const float* __restrict__ X, const float* __restrict__ W,
    const float* __restrict__ bias, float* __restrict__ out) {
    __shared__ float Xs[64 * 229];
    __shared__ float ws_w[4 * 232];
    int t = threadIdx.x, w = t >> 6, lane = t & 63;
    int r = blockIdx.x * 4 + w;
    float acc = 0.f;
    for (int c = 0; c < 3; c++) {
        int c0 = c * 228;
        __syncthreads();
        for (int i = t; i < 64 * 228; i += 256) {
            int bb = i / 228, kk = i - bb * 228;
            Xs[bb * 229 + kk] = X[bb * DC + c0 + kk];
        }
        for (int j = lane; j < 228; j += 64) ws_w[w * 232 + j] = W[r * DC + c0 + j];
        __syncthreads();
        const float* xrow = Xs + lane * 229;
        const float* wrow = ws_w + w * 232;
#pragma unroll 4
        for (int k = 0; k < 228; k++) acc += wrow[k] * xrow[k];
    }
    out[lane * 768 + r] = acc + bias[r];
}

// ---------------- GRU elementwise: s = gru(gi, gh, h) with mask ------------
__global__ __launch_bounds__(256) void k_gru(const float* __restrict__ gi,
                                             const float* __restrict__ gh,
                                             const float* __restrict__ h,
                                             const float* __restrict__ y_mask,
                                             float* __restrict__ outp) {
    int b = blockIdx.x, t = threadIdx.x;
    float hv = h[b * NH + t];
    float r = 1.f / (1.f + expf(-(gi[b * 768 + t] + gh[b * 768 + t])));
    float z = 1.f / (1.f + expf(-(gi[b * 768 + 256 + t] + gh[b * 768 + 256 + t])));
    float n = tanhf(gi[b * 768 + 512 + t] + r * gh[b * 768 + 512 + t]);
    float sv = (1.f - z) * n + z * hv;
    float m = y_mask[b];
    outp[b * NH + t] = m * sv + (1.f - m) * hv;
}

// ---------------- K2: fused attention-energy GEMM (bf16 MFMA) --------------
// block: (p-tile 64, b). wave w: a in [w*128,+128). A-frags direct from
// global A_pack (frag-major, coalesced 1KB/instr). B double-buffered in LDS.
#define LDW 40
__global__ __launch_bounds__(256, 2) void k_att(
    const unsigned short* __restrict__ Apack, const float* __restrict__ ctx,
    const float* __restrict__ G, const float* __restrict__ rb,
    const float* __restrict__ va, const float* __restrict__ va_b,
    const float* __restrict__ apast, float* __restrict__ alogit) {
    __shared__ __attribute__((aligned(16))) short lsB[2][64 * LDW];
    __shared__ float ap_s[18 * 50];
    __shared__ float part_s[4 * 64];
    int b = blockIdx.y;
    int p0 = blockIdx.x * 64;
    int t = threadIdx.x;
    int w = t >> 6, lane = t & 63;
    int l15 = lane & 15, lg = lane >> 4;
    int pq = t & 15, kp = t >> 4;  // B-stage mapping: rows pq+16j, col-pair kp
    const float* ctx_b = ctx + (long)b * DC * HW_ + p0;

    for (int idx = t; idx < 900; idx += 256) {
        int hh = idx / 50, ww = idx % 50;
        float v = 0.f;
        if (hh >= 1 && hh <= HH_ && ww >= 1 && ww <= WW_)
            v = apast[b * HW_ + (hh - 1) * WW_ + (ww - 1)];
        ap_s[idx] = v;
    }

#define CTXLOAD(FA, FB, S)                                                   \
    do {                                                                     \
        int d_ = (S) * 32 + 2 * kp;                                          \
        const float* s0_ = ctx_b + (long)d_ * HW_ + pq;                      \
        bool g0_ = d_ < DC, g1_ = (d_ + 1) < DC;                             \
        _Pragma("unroll") for (int j_ = 0; j_ < 4; j_++) {                   \
            FA[j_] = g0_ ? s0_[16 * j_] : 0.f;                               \
            FB[j_] = g1_ ? s0_[HW_ + 16 * j_] : 0.f;                         \
        }                                                                    \
    } while (0)

#define STAGEW(FA, FB, BUF)                                                  \
    do {                                                                     \
        _Pragma("unroll") for (int j_ = 0; j_ < 4; j_++) {                   \
            __hip_bfloat16 lo_ = __float2bfloat16(FA[j_]);                   \
            __hip_bfloat16 hi_ = __float2bfloat16(FB[j_]);                   \
            ((unsigned*)lsB[BUF])[(pq + 16 * j_) * (LDW / 2) + kp] =         \
                (unsigned)(*(unsigned short*)&lo_) |                         \
                ((unsigned)(*(unsigned short*)&hi_) << 16);                  \
        }                                                                    \
    } while (0)

#define ALOAD(AF, S)                                                         \
    do {                                                                     \
        _Pragma("unroll") for (int i_ = 0; i_ < 8; i_++)                     \
            AF[i_] = *(const bf16x8*)(Apack +                                \
                ((long)((S)*512 + w * 128 + i_ * 16 + l15) * 32) + lg * 8);  \
    } while (0)

#define BREAD(BF, BUF)                                                       \
    do {                                                                     \
        _Pragma("unroll") for (int j_ = 0; j_ < 4; j_++)                     \
            BF[j_] = *(const bf16x8*)(&lsB[BUF][(j_ * 16 + l15) * LDW +      \
                                               lg * 8]);                     \
    } while (0)

#define MFMA8x4(AF, BF)                                                      \
    do {                                                                     \
        _Pragma("unroll") for (int i_ = 0; i_ < 8; i_++)                     \
            _Pragma("unroll") for (int j_ = 0; j_ < 4; j_++)                 \
                acc[i_][j_] = __builtin_amdgcn_mfma_f32_16x16x32_bf16(       \
                    AF[i_], BF[j_], acc[i_][j_], 0, 0, 0);                   \
    } while (0)

    f32x4 acc[8][4];
#pragma unroll
    for (int i = 0; i < 8; i++)
#pragma unroll
        for (int j = 0; j < 4; j++) acc[i][j] = {0.f, 0.f, 0.f, 0.f};

    float fa0[4], fb0[4], fa1[4], fb1[4];
    bf16x8 afr0[8], afr1[8], bfr[4];

    // prologue: stage step0, preload ctx(step1), A(step0)
    CTXLOAD(fa1, fb1, 0);
    ALOAD(afr0, 0);
    STAGEW(fa1, fb1, 0);
    CTXLOAD(fa1, fb1, 1);
    __syncthreads();

    for (int ss = 0; ss < NS; ss += 2) {
        // even step t = ss : reads buf0/afr0; stages step ss+1 from (fa1,fb1)
        if (ss + 2 < NS) CTXLOAD(fa0, fb0, ss + 2);
        ALOAD(afr1, ss + 1);
        BREAD(bfr, 0);
        STAGEW(fa1, fb1, 1);
        MFMA8x4(afr0, bfr);
        __syncthreads();
        // odd step t = ss+1 : reads buf1/afr1; stages step ss+2 from (fa0,fb0)
        if (ss + 3 < NS) CTXLOAD(fa1, fb1, ss + 3);
        if (ss + 2 < NS) {
            ALOAD(afr0, ss + 2);
            BREAD(bfr, 1);
            STAGEW(fa0, fb0, 0);
            MFMA8x4(afr1, bfr);
        } else {
            BREAD(bfr, 1);
            MFMA8x4(afr1, bfr);
        }
        __syncthreads();
    }

    // epilogue: + rowbias + 9-tap coverage, tanh, dot with va, reduce over a
    float partial[4] = {0.f, 0.f, 0.f, 0.f};
#pragma unroll
    for (int i = 0; i < 8; i++) {
#pragma unroll
        for (int r = 0; r < 4; r++) {
            int a = w * 128 + i * 16 + lg * 4 + r;
            float rbv = rb[b * DA + a];
            float vav = va[a];
            const float* Ga = G + a * 9;
            float g0 = Ga[0], g1 = Ga[1], g2 = Ga[2], g3 = Ga[3], g4 = Ga[4];
            float g5 = Ga[5], g6 = Ga[6], g7 = Ga[7], g8 = Ga[8];
#pragma unroll
            for (int j = 0; j < 4; j++) {
                int p = p0 + j * 16 + l15;
                int hh = p / WW_, ww = p % WW_;
                const float* ap = ap_s + hh * 50 + ww;
                float cov = g0 * ap[0] + g1 * ap[1] + g2 * ap[2] +
                            g3 * ap[50] + g4 * ap[51] + g5 * ap[52] +
                            g6 * ap[100] + g7 * ap[101] + g8 * ap[102];
                float e = tanhf(acc[i][j][r] + rbv + cov);
                partial[j] += vav * e;
            }
        }
    }
#pragma unroll
    for (int j = 0; j < 4; j++) {
        partial[j] += __shfl_xor(partial[j], 16);
        partial[j] += __shfl_xor(partial[j], 32);
    }
    if (lane < 16) {
#pragma unroll
        for (int j = 0; j < 4; j++) part_s[w * 64 + j * 16 + lane] = partial[j];
    }
    __syncthreads();
    if (t < 64) {
        float s = va_b[0] + part_s[t] + part_s[64 + t] + part_s[128 + t] +
                  part_s[192 + t];
        alogit[b * HW_ + p0 + t] = s;
    }
}

// ---------------- K3: softmax over 768 positions per b ---------------------
__global__ __launch_bounds__(256) void k_softmax(const float* __restrict__ alogit,
                                                 float* __restrict__ alpha) {
    __shared__ float red[16];
    int b = blockIdx.x, t = threadIdx.x;
    float v[3];
    float mx = -1e30f;
    for (int i = 0; i < 3; i++) {
        v[i] = alogit[b * HW_ + i * 256 + t];
        mx = fmaxf(mx, v[i]);
    }
    for (int off = 32; off > 0; off >>= 1) mx = fmaxf(mx, __shfl_down(mx, off));
    if ((t & 63) == 0) red[t >> 6] = mx;
    __syncthreads();
    if (t == 0) red[0] = fmaxf(fmaxf(red[0], red[1]), fmaxf(red[2], red[3]));
    __syncthreads();
    mx = red[0];
    float sum = 0.f;
    for (int i = 0; i < 3; i++) {
        v[i] = expf(v[i] - mx);
        sum += v[i];
    }
    for (int off = 32; off > 0; off >>= 1) sum += __shfl_down(sum, off);
    if ((t & 63) == 0) red[8 + (t >> 6)] = sum;
    __syncthreads();
    if (t == 0) red[8] = red[8] + red[9] + red[10] + red[11];
    __syncthreads();
    float inv = 1.f / red[8];
    for (int i = 0; i < 3; i++) alpha[b * HW_ + i * 256 + t] = v[i] * inv;
}

// ---------------- K4: ct[b,d] = sum_p ctx[b,d,p] * alpha[b,p] --------------
__global__ __launch_bounds__(256) void k_ct(const float* __restrict__ ctx,
                                            const float* __restrict__ alpha,
                                            float* __restrict__ ct) {
    __shared__ float al_s[HW_];
    int b = blockIdx.y;
    int dc0 = blockIdx.x * 114;
    int t = threadIdx.x;
    for (int i = t; i < HW_; i += 256) al_s[i] = alpha[b * HW_ + i];
    __syncthreads();
    int wave = t >> 6, lane = t & 63;
    for (int d = dc0 + wave; d < dc0 + 114; d += 4) {
        const float* row = &ctx[((long)b * DC + d) * HW_];
        float s = 0.f;
#pragma unroll
        for (int q = 0; q < 12; q++) s += row[lane + q * 64] * al_s[lane + q * 64];
        for (int off = 32; off > 0; off >>= 1) s += __shfl_down(s, off);
        if (lane == 0) ct[b * DC + d] = s;
    }
}

// ---------------- K5: logit rows: lg[b][r] = Wct[r]·ct + Wht[r]·s + ... ----
__global__ __launch_bounds__(256) void k_logit(
    const float* __restrict__ ctv, const float* __restrict__ s,
    const float* __restrict__ embedded, const float* __restrict__ Wct,
    const float* __restrict__ Wht, const float* __restrict__ Wct_b,
    const float* __restrict__ Wht_b, float* __restrict__ lg) {
    __shared__ float Xs[64 * 257];
    __shared__ float ws_w[4 * 232];
    int t = threadIdx.x, w = t >> 6, lane = t & 63;
    int r = blockIdx.x * 4 + w;
    float acc = 0.f;
    for (int c = 0; c < 3; c++) {
        int c0 = c * 228;
        __syncthreads();
        for (int i = t; i < 64 * 228; i += 256) {
            int bb = i / 228, kk = i - bb * 228;
            Xs[bb * 229 + kk] = ctv[bb * DC + c0 + kk];
        }
        for (int j = lane; j < 228; j += 64) ws_w[w * 232 + j] = Wct[r * DC + c0 + j];
        __syncthreads();
        const float* xrow = Xs + lane * 229;
        const float* wrow = ws_w + w * 232;
#pragma unroll 4
        for (int k = 0; k < 228; k++) acc += wrow[k] * xrow[k];
    }
    __syncthreads();
    for (int i = t; i < 64 * 256; i += 256) {
        int bb = i >> 8, k = i & 255;
        Xs[bb * 257 + k] = s[bb * 256 + k];
    }
    for (int j = lane; j < 256; j += 64) ws_w[w * 232 + (j & 227)] = 0.f;  // unused, keep shape
    *(f32x4*)(ws_w + w * 232 + ((lane * 4) % 228)) = *(f32x4*)(ws_w + w * 232 + ((lane * 4) % 228));
    __syncthreads();
    // second dot (K=256) with Wht staged into ws_w region reused in 2 passes
    const float* xrow = Xs + lane * 257;
    float acc2 = 0.f;
    {
        // stage Wht row in two halves of 128 into ws_w (fits 232? no -> use direct global, coalesced via lane-major chunks)
        // simple: wave-uniform global reads (scalar-cached)
        const float* wr = Wht + r * 256;
#pragma unroll 8
        for (int k = 0; k < 256; k++) acc2 += wr[k] * xrow[k];
    }
    lg[lane * 256 + r] = acc + acc2 + Wct_b[r] + Wht_b[r] + embedded[lane * 256 + r];
}

// ---------------- K6: maxout + W0 head -------------------------------------
__global__ __launch_bounds__(256) void k_head(const float* __restrict__ lg,
                                              const float* __restrict__ W0,
                                              const float* __restrict__ W0_b,
                                              float* __restrict__ out) {
    __shared__ float Xs[64 * 129];
    __shared__ float ws_w[4 * 132];
    int t = threadIdx.x, w = t >> 6, lane = t & 63;
    for (int i = t; i < 64 * 128; i += 256) {
        int bb = i >> 7, m = i & 127;
        Xs[bb * 129 + m] = fmaxf(lg[bb * 256 + 2 * m], lg[bb * 256 + 2 * m + 1]);
    }
    int r = blockIdx.x * 4 + w;
    ws_w[w * 132 + lane] = W0[r * 128 + lane];
    ws_w[w * 132 + 64 + lane] = W0[r * 128 + 64 + lane];
    __syncthreads();
    const float* xrow = Xs + lane * 129;
    const float* wrow = ws_w + w * 132;
    float acc = 0.f;
#pragma unroll 8
    for (int k = 0; k < 128; k++) acc += wrow[k] * xrow[k];
    out[lane * KV + r] = acc + W0_b[r];
}

extern "C" void kernel_launch(void* const* d_in, const int* in_sizes, int n_in,
                              void* d_out, int out_size, void* d_ws,
                              size_t ws_size, hipStream_t stream) {
    const int* y = (const int*)d_in[0];
    const float* y_mask = (const float*)d_in[1];
    const float* context = (const float*)d_in[2];
    const float* pre_hidden = (const float*)d_in[3];
    const float* alpha_past = (const float*)d_in[4];
    const float* emb = (const float*)d_in[5];
    const float* W_ih1 = (const float*)d_in[6];
    const float* W_hh1 = (const float*)d_in[7];
    const float* b_ih1 = (const float*)d_in[8];
    const float* b_hh1 = (const float*)d_in[9];
    const float* conv_Ua_w = (const float*)d_in[10];
    const float* conv_Ua_b = (const float*)d_in[11];
    const float* Wa = (const float*)d_in[12];
    const float* conv_Q_w = (const float*)d_in[13];
    const float* Uf = (const float*)d_in[14];
    const float* Uf_b = (const float*)d_in[15];
    const float* va = (const float*)d_in[16];
    const float* va_b = (const float*)d_in[17];
    const float* W_ih2 = (const float*)d_in[18];
    const float* W_hh2 = (const float*)d_in[19];
    const float* b_ih2 = (const float*)d_in[20];
    const float* b_hh2 = (const float*)d_in[21];
    const float* Wct = (const float*)d_in[22];
    const float* Wct_b = (const float*)d_in[23];
    const float* Wht = (const float*)d_in[24];
    const float* Wht_b = (const float*)d_in[25];
    const float* W0 = (const float*)d_in[26];
    const float* W0_b = (const float*)d_in[27];

    float* ws = (float*)d_ws;
    float* out = (float*)d_out;
    float* G = ws + WS_G;
    float* rbias = ws + WS_RB;
    float* embedded = ws + WS_EMB;
    float* s_hat = ws + WS_SH;
    float* alogit = ws + WS_AL;
    float* ctv = ws + WS_CT;
    unsigned short* Apack = (unsigned short*)(ws + WS_APACK);
    float* gi = ws + WS_GI;
    float* gh = ws + WS_GH;
    float* lg = ws + WS_LG;
    float* s_out = out + 8192;       // output 1: s
    float* alpha_out = out + 24576;  // output 2: alpha

    k_G<<<dim3(18), dim3(256), 0, stream>>>(Uf, conv_Q_w, G);
    k_prepA<<<dim3((NS * DA * 32 + 255) / 256), dim3(256), 0, stream>>>(
        conv_Ua_w, Apack);
    k_emb<<<dim3(64), dim3(256), 0, stream>>>(y, emb, embedded);
    k_rows256<<<dim3(192), dim3(256), 0, stream>>>(embedded, W_ih1, b_ih1,
                                                   nullptr, gi, 768);
    k_rows256<<<dim3(192), dim3(256), 0, stream>>>(pre_hidden, W_hh1, b_hh1,
                                                   nullptr, gh, 768);
    k_gru<<<dim3(64), dim3(256), 0, stream>>>(gi, gh, pre_hidden, y_mask, s_hat);
    k_rows256<<<dim3(128), dim3(256), 0, stream>>>(s_hat, Wa, conv_Ua_b, Uf_b,
                                                   rbias, 512);
    k_att<<<dim3(12, 64), dim3(256), 0, stream>>>(Apack, context, G, rbias, va,
                                                  va_b, alpha_past, alogit);
    k_softmax<<<dim3(64), dim3(256), 0, stream>>>(alogit, alpha_out);
    k_ct<<<dim3(6, 64), dim3(256), 0, stream>>>(context, alpha_out, ctv);
    k_rows684<<<dim3(192), dim3(256), 0, stream>>>(ctv, W_ih2, b_ih2, gi);
    k_rows256<<<dim3(192), dim3(256), 0, stream>>>(s_hat, W_hh2, b_hh2, nullptr,
                                                   gh, 768);
    k_gru<<<dim3(64), dim3(256), 0, stream>>>(gi, gh, s_hat, y_mask, s_out);
    k_logit<<<dim3(64), dim3(256), 0, stream>>>(ctv, s_out, embedded, Wct, Wht,
                                                Wct_b, Wht_b, lg);
    k_head<<<dim3(32), dim3(256), 0, stream>>>(lg, W0, W0_b, out);
}